// Round 4
// baseline (634.379 us; speedup 1.0000x reference)
//
#include <hip/hip_runtime.h>

// ---- problem constants ----
#define V_DIM   2048
#define Q_DIM   1024
#define NUM_HID 1024
#define BB 64
#define KK 12
#define NN 36
#define M_ROWS (BB*KK*NN)    // 27648 = 216 * 128, exact
#define BKROWS (BB*KK)       // 768   = 6 * 128,   exact

typedef unsigned short u16;
typedef __bf16 bf16x8  __attribute__((ext_vector_type(8)));
typedef u16    ushort8 __attribute__((ext_vector_type(8)));
typedef float  floatx4 __attribute__((ext_vector_type(4)));

#define AS1 __attribute__((address_space(1)))
#define AS3 __attribute__((address_space(3)))

// async 16B global->LDS (HW writes lane's data at lds base + lane*16)
__device__ __forceinline__ void gl_lds16(const void* g, void* l) {
    __builtin_amdgcn_global_load_lds((const AS1 void*)g, (AS3 void*)l, 16, 0, 0);
}

// fp32 -> bf16, round-to-nearest-even
__device__ __forceinline__ u16 f2bf(float f) {
    unsigned u = __float_as_uint(f);
    u += 0x7fffu + ((u >> 16) & 1u);
    return (u16)(u >> 16);
}

// ---- W1 fp32 (1024 x 3072) -> bf16 W1v (1024x2048) + W1q (1024x1024), fused ||W1||^2 ----
__global__ void convert_w1_kernel(const float* __restrict__ W1,
                                  u16* __restrict__ W1v, u16* __restrict__ W1q,
                                  float* __restrict__ acc)
{
    int s = blockIdx.x * 256 + threadIdx.x;          // grid 1536*256 = 393216 exact
    int h = s / 384, g = s % 384;
    const float4* p = (const float4*)(W1 + (size_t)h * (V_DIM + Q_DIM) + g * 8);
    float4 a = p[0], b = p[1];
    ushort8 o;
    o[0]=f2bf(a.x); o[1]=f2bf(a.y); o[2]=f2bf(a.z); o[3]=f2bf(a.w);
    o[4]=f2bf(b.x); o[5]=f2bf(b.y); o[6]=f2bf(b.z); o[7]=f2bf(b.w);
    if (g < 256) *(ushort8*)(W1v + (size_t)h * V_DIM + g * 8) = o;
    else         *(ushort8*)(W1q + (size_t)h * Q_DIM + (g - 256) * 8) = o;
    float ss = a.x*a.x + a.y*a.y + a.z*a.z + a.w*a.w
             + b.x*b.x + b.y*b.y + b.z*b.z + b.w*b.w;
    #pragma unroll
    for (int off = 32; off > 0; off >>= 1) ss += __shfl_down(ss, off);
    if ((threadIdx.x & 63) == 0) atomicAdd(acc, ss);
}

// ---- v fp32 [27648][2048] -> bf16, q fp32 [768][1024] -> bf16 (one streaming pass) ----
// ROUND-3 BUGFIX: VSLOTS is 7,077,888 (27648*2048/8), NOT 3,538,944 — the
// old 14208-block grid left half of vbf as 0xAA poison (the entire failure).
#define VSLOTS (M_ROWS * V_DIM / 8)                  // 7,077,888
#define QSLOTS (BKROWS * Q_DIM / 8)                  // 98,304
// (VSLOTS+QSLOTS)/256 = 28032 blocks exact
__global__ void convert_vq_kernel(const float* __restrict__ v, const float* __restrict__ q,
                                  u16* __restrict__ vbf, u16* __restrict__ qbf)
{
    int s = blockIdx.x * 256 + threadIdx.x;
    const float* src;
    u16* dst;
    if (s < VSLOTS) { src = v; dst = vbf; }
    else            { src = q; dst = qbf; s -= VSLOTS; }
    const float4* p = (const float4*)src + (size_t)s * 2;
    float4 a = p[0], b = p[1];
    ushort8 o;
    o[0]=f2bf(a.x); o[1]=f2bf(a.y); o[2]=f2bf(a.z); o[3]=f2bf(a.w);
    o[4]=f2bf(b.x); o[5]=f2bf(b.y); o[6]=f2bf(b.z); o[7]=f2bf(b.w);
    *(ushort8*)(dst + (size_t)s * 8) = o;
}

// ---- ||W2||^2 + final scales: wsf[2]=g1/||W1||, wsf[3]=g2/||W2|| ----
__global__ void scale_kernel(const float* __restrict__ W2, const float* __restrict__ g1,
                             const float* __restrict__ g2, float* __restrict__ wsf)
{
    float v = W2[threadIdx.x];          // blockDim = 1024
    float s = v * v;
    #pragma unroll
    for (int off = 32; off > 0; off >>= 1) s += __shfl_down(s, off);
    __shared__ float red[16];
    if ((threadIdx.x & 63) == 0) red[threadIdx.x >> 6] = s;
    __syncthreads();
    if (threadIdx.x == 0) {
        float t = 0.f;
        #pragma unroll
        for (int u = 0; u < 16; u++) t += red[u];
        wsf[2] = g1[0] / sqrtf(wsf[0]);
        wsf[3] = g2[0] / sqrtf(t);
    }
}

// ---- MFMA GEMM: A,B bf16 staged via global_load_lds width-16 with XOR swizzle.
// LDS tile 128x64 bf16 = 1024 chunks of 16B; logical chunk (row, g) lives at
// physical chunk row*8 + (g ^ (row&7)). The permutation is applied on the
// per-lane GLOBAL gather address (free); fragment ds_read_b128 then has 8
// distinct bank-starts across the 16 quad-lanes -> 2-way aliasing (free,
// m136) instead of 16-way (5.7x) for the unswizzled layout.
// (Round-2/3 identical-absmax evidence: swizzle is output-correct on HW.)
// MAIN=true : fused epilogue partial[row][bx*2+wn] = sum_cols relu(s1*(acc+hq)+b1)*W2
// MAIN=false: raw acc to outp[row*1024+col] (the hq pass)
template<int GK, bool MAIN>
__global__ __launch_bounds__(256, 3)
void gemm_kernel(const u16* __restrict__ Abf,    // [M][GK] bf16 row-major
                 const u16* __restrict__ Bsrc,   // [1024][GK] bf16 n-major
                 float*       __restrict__ outp,
                 const float* __restrict__ hq,
                 const float* __restrict__ b1,
                 const float* __restrict__ W2,
                 const float* __restrict__ scl)
{
    __shared__ __align__(16) u16 As[128 * 64];
    __shared__ __align__(16) u16 Bs[128 * 64];

    const int tid  = threadIdx.x;
    const int lane = tid & 63;
    const int wv   = tid >> 6;
    const int wm   = wv & 1;          // wave row (0..1)
    const int wn   = wv >> 1;         // wave col (0..1)
    const int quad = lane >> 4;
    const int l15  = lane & 15;
    const int m0   = blockIdx.y * 128;
    const int n0   = blockIdx.x * 128;

    // staging map: wave wv, instr j covers physical chunks p = (wv*4+j)*64+lane;
    // that slot holds logical (row = p>>3, g = (p&7) ^ (row&7))
    int rS[4], gS[4];
    #pragma unroll
    for (int j = 0; j < 4; j++) {
        int p = (wv * 4 + j) * 64 + lane;
        rS[j] = p >> 3;
        gS[j] = (p & 7) ^ (rS[j] & 7);
    }

    floatx4 acc[4][4];
    #pragma unroll
    for (int i = 0; i < 4; i++)
        #pragma unroll
        for (int j = 0; j < 4; j++)
            acc[i][j] = (floatx4){0.f, 0.f, 0.f, 0.f};

    for (int kt = 0; kt < GK / 64; ++kt) {
        const int k0 = kt * 64;
        __syncthreads();                       // all waves done reading prev tile
        #pragma unroll
        for (int j = 0; j < 4; j++) {
            gl_lds16(Abf + (size_t)(m0 + rS[j]) * GK + k0 + gS[j] * 8,
                     (char*)As + (wv * 4 + j) * 1024);
            gl_lds16(Bsrc + (size_t)(n0 + rS[j]) * GK + k0 + gS[j] * 8,
                     (char*)Bs + (wv * 4 + j) * 1024);
        }
        __syncthreads();                       // drains vmcnt -> LDS visible
        #pragma unroll
        for (int ks = 0; ks < 2; ++ks) {
            bf16x8 af[4], bfr[4];
            #pragma unroll
            for (int i = 0; i < 4; i++) {
                int row = wm * 64 + i * 16 + l15;   // row&7 == l15&7
                af[i] = *(const bf16x8*)(&As[row * 64 + (((ks * 4 + quad) ^ (l15 & 7)) * 8)]);
            }
            #pragma unroll
            for (int j = 0; j < 4; j++) {
                int col = wn * 64 + j * 16 + l15;
                bfr[j] = *(const bf16x8*)(&Bs[col * 64 + (((ks * 4 + quad) ^ (l15 & 7)) * 8)]);
            }
            #pragma unroll
            for (int i = 0; i < 4; i++)
                #pragma unroll
                for (int j = 0; j < 4; j++)
                    acc[i][j] = __builtin_amdgcn_mfma_f32_16x16x32_bf16(af[i], bfr[j], acc[i][j], 0, 0, 0);
        }
    }

    if constexpr (MAIN) {
        const float s1 = scl[2];
        int   cg[4];
        float w2v[4], b1v[4];
        #pragma unroll
        for (int j = 0; j < 4; j++) {
            cg[j]  = n0 + wn * 64 + j * 16 + l15;
            w2v[j] = W2[cg[j]];
            b1v[j] = b1[cg[j]];
        }
        #pragma unroll
        for (int i = 0; i < 4; i++) {
            #pragma unroll
            for (int r = 0; r < 4; r++) {
                const int mg = m0 + wm * 64 + i * 16 + quad * 4 + r;
                const int bk = mg / NN;
                float p = 0.f;
                #pragma unroll
                for (int j = 0; j < 4; j++) {
                    float pre = s1 * (acc[i][j][r] + hq[(size_t)bk * NUM_HID + cg[j]]) + b1v[j];
                    p += fmaxf(pre, 0.f) * w2v[j];
                }
                p += __shfl_xor(p, 1);
                p += __shfl_xor(p, 2);
                p += __shfl_xor(p, 4);
                p += __shfl_xor(p, 8);
                if (l15 == 0)
                    outp[(size_t)mg * 16 + blockIdx.x * 2 + wn] = p;
            }
        }
    } else {
        #pragma unroll
        for (int i = 0; i < 4; i++)
            #pragma unroll
            for (int r = 0; r < 4; r++) {
                const int mg = m0 + wm * 64 + i * 16 + quad * 4 + r;
                #pragma unroll
                for (int j = 0; j < 4; j++) {
                    const int c = n0 + wn * 64 + j * 16 + l15;
                    outp[(size_t)mg * NUM_HID + c] = acc[i][j][r];
                }
            }
    }
}

// ---- softmax over K=12 per (b,n); logits = s2*sum(partials) + b2 ----
__global__ void softmax_kernel(const float* __restrict__ part,
                               const float* __restrict__ scl,
                               const float* __restrict__ b2,
                               float* __restrict__ out)
{
    int t = blockIdx.x * 256 + threadIdx.x;   // grid 9*256 = 2304 exact
    if (t >= BB * NN) return;
    int b = t / NN, n = t % NN;
    float s2 = scl[3], bias = b2[0];
    float lg[KK];
    float mx = -1e30f;
    #pragma unroll
    for (int k = 0; k < KK; k++) {
        int m = (b * KK + k) * NN + n;
        const float4* pp = (const float4*)(part + (size_t)m * 16);
        float4 a0 = pp[0], a1 = pp[1], a2 = pp[2], a3 = pp[3];
        float s = (a0.x + a0.y + a0.z + a0.w) + (a1.x + a1.y + a1.z + a1.w)
                + (a2.x + a2.y + a2.z + a2.w) + (a3.x + a3.y + a3.z + a3.w);
        lg[k] = s2 * s + bias;
        mx = fmaxf(mx, lg[k]);
    }
    float den = 0.f;
    #pragma unroll
    for (int k = 0; k < KK; k++) { lg[k] = expf(lg[k] - mx); den += lg[k]; }
    float inv = 1.0f / den;
    #pragma unroll
    for (int k = 0; k < KK; k++) out[(size_t)((b * KK + k) * NN + n)] = lg[k] * inv;
}

extern "C" void kernel_launch(void* const* d_in, const int* in_sizes, int n_in,
                              void* d_out, int out_size, void* d_ws, size_t ws_size,
                              hipStream_t stream)
{
    (void)in_sizes; (void)n_in; (void)out_size; (void)ws_size;
    const float* v  = (const float*)d_in[0];
    const float* q  = (const float*)d_in[1];
    const float* W1 = (const float*)d_in[2];
    const float* g1 = (const float*)d_in[3];
    const float* b1 = (const float*)d_in[4];
    const float* W2 = (const float*)d_in[5];
    const float* g2 = (const float*)d_in[6];
    const float* b2 = (const float*)d_in[7];
    float* out = (float*)d_out;

    // ws layout (bytes, all offsets 16-aligned):
    //   0          : 4 floats [w1_sumsq, unused, s1, s2]
    //   16         : part fp32 [27648][16]   1,769,472
    //   1,769,488  : hq   fp32 [768][1024]   3,145,728
    //   4,915,216  : W1v  bf16 [1024][2048]  4,194,304
    //   9,109,520  : W1q  bf16 [1024][1024]  2,097,152
    //   11,206,672 : qbf  bf16 [768][1024]   1,572,864
    //   12,779,536 : vbf  bf16 [27648][2048] 113,246,208   -> total ~126.0 MB
    char*  ws   = (char*)d_ws;
    float* wsf  = (float*)ws;
    float* part = (float*)(ws + 16);
    float* hqb  = (float*)(ws + 1769488);
    u16*   W1v  = (u16*)  (ws + 4915216);
    u16*   W1q  = (u16*)  (ws + 9109520);
    u16*   qbf  = (u16*)  (ws + 11206672);
    u16*   vbf  = (u16*)  (ws + 12779536);

    hipMemsetAsync(d_ws, 0, 16, stream);
    convert_w1_kernel<<<1536, 256, 0, stream>>>(W1, W1v, W1q, wsf);
    scale_kernel<<<1, 1024, 0, stream>>>(W2, g1, g2, wsf);
    convert_vq_kernel<<<28032, 256, 0, stream>>>(v, q, vbf, qbf);
    // hq = q @ W1q^T (raw, unscaled): grid (8 ntiles, 6 mtiles)
    gemm_kernel<Q_DIM, false><<<dim3(8, 6), 256, 0, stream>>>(qbf, W1q, hqb, nullptr, nullptr, nullptr, wsf);
    // main: per-row partial logits
    gemm_kernel<V_DIM, true><<<dim3(8, 216), 256, 0, stream>>>(vbf, W1v, part, hqb, b1, W2, wsf);
    softmax_kernel<<<9, 256, 0, stream>>>(part, wsf, b2, out);
}